// Round 7
// baseline (457.494 us; speedup 1.0000x reference)
//
#include <hip/hip_runtime.h>

#define E_DIM 512
#define U_DIM 64
#define T_DIM 8
#define A_DIM 32
#define NB    10
#define BATCH 8192
#define G2    8                        // elements per stage-2 block
#define S2_BLOCKS (BATCH / G2 + T_DIM)

// workspace layout
#define WS_PERM  0                     // [8192] ints: permutation grouped by type
#define WS_START 8192                  // [9] ints: element prefix per type
#define WS_BLK   8201                  // [9] ints: stage-2 block prefix per type
#define WS_IPAD  8256                  // pad; floats (agg[B][64]) start here
#define WS_TOTAL_BYTES ((size_t)(WS_IPAD + BATCH * U_DIM) * 4)

// ---------------------------------------------------------------------------
// Pass 0: counting sort of batch elements by type (order within type
// irrelevant -> atomic nondeterminism is harmless).
// ---------------------------------------------------------------------------
__global__ void bucket_kernel(const int* __restrict__ train_types,
                              int* __restrict__ ws)
{
    __shared__ int cnt[T_DIM], offs[T_DIM], startS[T_DIM];
    const int tid  = threadIdx.x;        // 1024 threads
    const int lane = tid & 63;

    if (tid < T_DIM) { cnt[tid] = 0; offs[tid] = 0; }
    __syncthreads();

    int ty[8];
    #pragma unroll
    for (int it = 0; it < 8; ++it) ty[it] = train_types[tid + it * 1024];

    #pragma unroll
    for (int it = 0; it < 8; ++it) {
        #pragma unroll
        for (int t = 0; t < T_DIM; ++t) {
            const unsigned long long m = __ballot(ty[it] == t);
            if (m && lane == __ffsll((unsigned long long)m) - 1)
                atomicAdd(&cnt[t], __popcll(m));
        }
    }
    __syncthreads();

    if (tid == 0) {
        int s = 0, bs = 0;
        for (int t = 0; t < T_DIM; ++t) {
            startS[t] = s;
            ws[WS_START + t] = s;
            ws[WS_BLK + t]   = bs;
            s  += cnt[t];
            bs += (cnt[t] + G2 - 1) / G2;
        }
        ws[WS_START + T_DIM] = s;
        ws[WS_BLK + T_DIM]   = bs;
    }
    __syncthreads();

    #pragma unroll
    for (int it = 0; it < 8; ++it) {
        const int idx = tid + it * 1024;
        const int t   = ty[it];
        #pragma unroll
        for (int tt = 0; tt < T_DIM; ++tt) {
            const unsigned long long m = __ballot(t == tt);
            if (t == tt) {
                const int leader = __ffsll((unsigned long long)m) - 1;
                int base;
                if (lane == leader) base = atomicAdd(&offs[tt], __popcll(m));
                base = __shfl(base, leader, 64);
                const int rank = __popcll(m & ((1ull << lane) - 1ull));
                ws[WS_PERM + startS[tt] + base + rank] = idx;
            }
        }
    }
}

// ---------------------------------------------------------------------------
// Stage 1: per-element blocks (8192). float4 gather -- 16 lanes cover one
// 256B row, a wave loads 4 rows per instruction (6 loads/wave vs 20), then a
// 2-level shfl_xor cross-group reduction. Attention/softmax/agg unchanged.
// ---------------------------------------------------------------------------
__launch_bounds__(256, 8)
__global__ void gatne_stage1(
    const float* __restrict__ node_type_embeddings, // [N, 8, 64]
    const float* __restrict__ trans_weights_s1,     // [8, 64, 32]
    const float* __restrict__ trans_weights_s2,     // [8, 32]
    const int*   __restrict__ train_types,          // [B]
    const int*   __restrict__ node_neigh,           // [B, 8, 10]
    float*       __restrict__ agg_out)              // [B, 64] in ws
{
    const int b    = blockIdx.x;
    const int tid  = threadIdx.x;
    const int lane = tid & 63;
    const int wv   = tid >> 6;     // wave 0..3 handles types wv and wv+4

    __shared__ float s_nte[T_DIM][U_DIM];   // 2 KB
    __shared__ float s_att[T_DIM];

    const int ty = train_types[b];

    // neighbor indices: lanes 0..63 hold nn[0..63], lanes 0..15 hold nn[64..79]
    const int* nn = node_neigh + (size_t)b * (T_DIM * NB);
    const int i0 = nn[lane];
    const int i1 = (lane < (T_DIM * NB - 64)) ? nn[64 + lane] : 0;

    // ---- float4 gather: group g = lane>>4 covers rows {g, 4+g, 8+g} ----
    const int g  = lane >> 4;              // 0..3
    const int u4 = (lane & 15) * 4;        // element offset within row
    const int tA = wv, tB = wv + 4;

    float4 accA, accB;
    {
        const int r0 = g, r1 = 4 + g, r2 = 8 + g;          // r2 valid iff < 10
        // type A: j = tA*10 + r  (max 41 -> always from i0)
        const int iA0 = __shfl(i0, tA * NB + r0, 64);
        const int iA1 = __shfl(i0, tA * NB + r1, 64);
        const int iA2 = __shfl(i0, tA * NB + r2, 64);
        // type B: j = tB*10 + r  (40..81 -> may need i1)
        const int jB0 = tB * NB + r0, jB1 = tB * NB + r1, jB2 = tB * NB + r2;
        const int iB0 = (jB0 < 64) ? __shfl(i0, jB0, 64) : __shfl(i1, (jB0 - 64) & 63, 64);
        const int iB1 = (jB1 < 64) ? __shfl(i0, jB1, 64) : __shfl(i1, (jB1 - 64) & 63, 64);
        const int iB2 = (jB2 < 64) ? __shfl(i0, jB2, 64) : __shfl(i1, (jB2 - 64) & 63, 64);

        const float4 a0 = *(const float4*)(node_type_embeddings + (size_t)iA0 * (T_DIM * U_DIM) + tA * U_DIM + u4);
        const float4 a1 = *(const float4*)(node_type_embeddings + (size_t)iA1 * (T_DIM * U_DIM) + tA * U_DIM + u4);
        float4 a2 = make_float4(0.f, 0.f, 0.f, 0.f);
        if (r2 < NB)
            a2 = *(const float4*)(node_type_embeddings + (size_t)iA2 * (T_DIM * U_DIM) + tA * U_DIM + u4);

        const float4 b0 = *(const float4*)(node_type_embeddings + (size_t)iB0 * (T_DIM * U_DIM) + tB * U_DIM + u4);
        const float4 b1 = *(const float4*)(node_type_embeddings + (size_t)iB1 * (T_DIM * U_DIM) + tB * U_DIM + u4);
        float4 b2 = make_float4(0.f, 0.f, 0.f, 0.f);
        if (r2 < NB)
            b2 = *(const float4*)(node_type_embeddings + (size_t)iB2 * (T_DIM * U_DIM) + tB * U_DIM + u4);

        accA.x = a0.x + a1.x + a2.x;  accA.y = a0.y + a1.y + a2.y;
        accA.z = a0.z + a1.z + a2.z;  accA.w = a0.w + a1.w + a2.w;
        accB.x = b0.x + b1.x + b2.x;  accB.y = b0.y + b1.y + b2.y;
        accB.z = b0.z + b1.z + b2.z;  accB.w = b0.w + b1.w + b2.w;
    }
    // reduce across the 4 row-groups (lane^16, lane^32)
    accA.x += __shfl_xor(accA.x, 16, 64); accA.x += __shfl_xor(accA.x, 32, 64);
    accA.y += __shfl_xor(accA.y, 16, 64); accA.y += __shfl_xor(accA.y, 32, 64);
    accA.z += __shfl_xor(accA.z, 16, 64); accA.z += __shfl_xor(accA.z, 32, 64);
    accA.w += __shfl_xor(accA.w, 16, 64); accA.w += __shfl_xor(accA.w, 32, 64);
    accB.x += __shfl_xor(accB.x, 16, 64); accB.x += __shfl_xor(accB.x, 32, 64);
    accB.y += __shfl_xor(accB.y, 16, 64); accB.y += __shfl_xor(accB.y, 32, 64);
    accB.z += __shfl_xor(accB.z, 16, 64); accB.z += __shfl_xor(accB.z, 32, 64);
    accB.w += __shfl_xor(accB.w, 16, 64); accB.w += __shfl_xor(accB.w, 32, 64);

    if (lane < 16) {
        *(float4*)&s_nte[tA][u4] = accA;
        *(float4*)&s_nte[tB][u4] = accB;
    }
    __syncthreads();

    // ---- attention scores: thread (t = tid>>5, a = tid&31) ----
    {
        const int t = tid >> 5;
        const int a = tid & 31;
        const float* w1 = trans_weights_s1 + (size_t)ty * (U_DIM * A_DIM) + a;
        float h = 0.f;
        #pragma unroll
        for (int u = 0; u < U_DIM; ++u)
            h = fmaf(s_nte[t][u], w1[u * A_DIM], h);
        float val = tanhf(h) * trans_weights_s2[ty * A_DIM + a];
        #pragma unroll
        for (int off = 16; off > 0; off >>= 1)
            val += __shfl_down(val, off, 32);
        if (a == 0) s_att[t] = val;
    }
    __syncthreads();

    // ---- softmax (redundant per lane) fused with agg: threads 0..63 ----
    if (tid < U_DIM) {
        const float sc0 = s_att[0], sc1 = s_att[1], sc2 = s_att[2], sc3 = s_att[3];
        const float sc4 = s_att[4], sc5 = s_att[5], sc6 = s_att[6], sc7 = s_att[7];
        const float m = fmaxf(fmaxf(fmaxf(sc0, sc1), fmaxf(sc2, sc3)),
                              fmaxf(fmaxf(sc4, sc5), fmaxf(sc6, sc7)));
        const float x0 = __expf(sc0 - m), x1 = __expf(sc1 - m);
        const float x2 = __expf(sc2 - m), x3 = __expf(sc3 - m);
        const float x4 = __expf(sc4 - m), x5 = __expf(sc5 - m);
        const float x6 = __expf(sc6 - m), x7 = __expf(sc7 - m);
        const float inv_sum = 1.f / (x0 + x1 + x2 + x3 + x4 + x5 + x6 + x7);
        const float acc = x0 * s_nte[0][tid] + x1 * s_nte[1][tid]
                        + x2 * s_nte[2][tid] + x3 * s_nte[3][tid]
                        + x4 * s_nte[4][tid] + x5 * s_nte[5][tid]
                        + x6 * s_nte[6][tid] + x7 * s_nte[7][tid];
        agg_out[(size_t)b * U_DIM + tid] = acc * inv_sum;   // 256B coalesced
    }
}

// ---------------------------------------------------------------------------
// Stage 2: grouped matvec. G2=8 same-type elements per block; each half-block
// (128 threads, float4 lanes) computes 4 elements from ONE shared w[ty]
// float4 stream (8x less L2 w-traffic than per-element).
// ---------------------------------------------------------------------------
__launch_bounds__(256, 8)
__global__ void gatne_stage2(
    const float* __restrict__ node_embeddings,      // [N, 512]
    const float* __restrict__ trans_weights,        // [8, 64, 512]
    const int*   __restrict__ train_inputs,         // [B]
    const int*   __restrict__ ws_i,
    const float* __restrict__ agg,                  // [B, 64] in ws
    float*       __restrict__ out)                  // [B, 512]
{
    const int tid  = threadIdx.x;
    const int lane = tid & 63;
    const int wv   = tid >> 6;      // 0..3
    const int half = tid >> 7;      // 0,1 ; half h owns elements 4h..4h+3
    const int g0   = half * 4;
    const int e0   = (tid & 127) * 4;

    __shared__ __align__(16) float s_agg[U_DIM][G2];   // [64][8] = 2 KB
    __shared__ float s_red[4][4];

    const int j = blockIdx.x;
    if (j >= ws_i[WS_BLK + T_DIM]) return;

    int t = 0;
    #pragma unroll
    for (int k = 1; k < T_DIM; ++k) if (j >= ws_i[WS_BLK + k]) t = k;
    const int eBase = ws_i[WS_START + t] + (j - ws_i[WS_BLK + t]) * G2;
    const int nE    = min(G2, ws_i[WS_START + t + 1] - eBase);

    // cooperative agg->LDS: 32-lane group per element, float2 each (coalesced)
    {
        const int g  = tid >> 5;                       // 0..7
        const int u2 = (tid & 31) * 2;
        const int eg = ws_i[WS_PERM + eBase + min(g, nE - 1)];
        const float2 v = *(const float2*)(agg + (size_t)eg * U_DIM + u2);
        s_agg[u2][g]     = v.x;
        s_agg[u2 + 1][g] = v.y;
    }

    const int eA = ws_i[WS_PERM + eBase + min(g0 + 0, nE - 1)];
    const int eB = ws_i[WS_PERM + eBase + min(g0 + 1, nE - 1)];
    const int eC = ws_i[WS_PERM + eBase + min(g0 + 2, nE - 1)];
    const int eD = ws_i[WS_PERM + eBase + min(g0 + 3, nE - 1)];

    float4 v0 = *(const float4*)(node_embeddings + (size_t)train_inputs[eA] * E_DIM + e0);
    float4 v1 = *(const float4*)(node_embeddings + (size_t)train_inputs[eB] * E_DIM + e0);
    float4 v2 = *(const float4*)(node_embeddings + (size_t)train_inputs[eC] * E_DIM + e0);
    float4 v3 = *(const float4*)(node_embeddings + (size_t)train_inputs[eD] * E_DIM + e0);

    __syncthreads();   // s_agg ready

    const float* wb = trans_weights + (size_t)t * (U_DIM * E_DIM) + e0;
    #pragma unroll 4
    for (int u = 0; u < U_DIM; ++u) {
        const float4 w4 = *(const float4*)(wb + (size_t)u * E_DIM);
        const float4 ag = *(const float4*)(&s_agg[u][g0]);   // b128 broadcast
        v0.x = fmaf(ag.x, w4.x, v0.x); v0.y = fmaf(ag.x, w4.y, v0.y);
        v0.z = fmaf(ag.x, w4.z, v0.z); v0.w = fmaf(ag.x, w4.w, v0.w);
        v1.x = fmaf(ag.y, w4.x, v1.x); v1.y = fmaf(ag.y, w4.y, v1.y);
        v1.z = fmaf(ag.y, w4.z, v1.z); v1.w = fmaf(ag.y, w4.w, v1.w);
        v2.x = fmaf(ag.z, w4.x, v2.x); v2.y = fmaf(ag.z, w4.y, v2.y);
        v2.z = fmaf(ag.z, w4.z, v2.z); v2.w = fmaf(ag.z, w4.w, v2.w);
        v3.x = fmaf(ag.w, w4.x, v3.x); v3.y = fmaf(ag.w, w4.y, v3.y);
        v3.z = fmaf(ag.w, w4.z, v3.z); v3.w = fmaf(ag.w, w4.w, v3.w);
    }

    float ss0 = v0.x*v0.x + v0.y*v0.y + v0.z*v0.z + v0.w*v0.w;
    float ss1 = v1.x*v1.x + v1.y*v1.y + v1.z*v1.z + v1.w*v1.w;
    float ss2 = v2.x*v2.x + v2.y*v2.y + v2.z*v2.z + v2.w*v2.w;
    float ss3 = v3.x*v3.x + v3.y*v3.y + v3.z*v3.z + v3.w*v3.w;
    #pragma unroll
    for (int off = 32; off > 0; off >>= 1) {
        ss0 += __shfl_xor(ss0, off, 64);
        ss1 += __shfl_xor(ss1, off, 64);
        ss2 += __shfl_xor(ss2, off, 64);
        ss3 += __shfl_xor(ss3, off, 64);
    }
    if (lane == 0) {
        s_red[wv][0] = ss0; s_red[wv][1] = ss1;
        s_red[wv][2] = ss2; s_red[wv][3] = ss3;
    }
    __syncthreads();

    const int h2 = half * 2;
    const float iv0 = 1.f / fmaxf(sqrtf(s_red[h2][0] + s_red[h2+1][0]), 1e-12f);
    const float iv1 = 1.f / fmaxf(sqrtf(s_red[h2][1] + s_red[h2+1][1]), 1e-12f);
    const float iv2 = 1.f / fmaxf(sqrtf(s_red[h2][2] + s_red[h2+1][2]), 1e-12f);
    const float iv3 = 1.f / fmaxf(sqrtf(s_red[h2][3] + s_red[h2+1][3]), 1e-12f);

    if (g0 + 0 < nE) { float4 o; o.x=v0.x*iv0; o.y=v0.y*iv0; o.z=v0.z*iv0; o.w=v0.w*iv0;
        *(float4*)(out + (size_t)eA * E_DIM + e0) = o; }
    if (g0 + 1 < nE) { float4 o; o.x=v1.x*iv1; o.y=v1.y*iv1; o.z=v1.z*iv1; o.w=v1.w*iv1;
        *(float4*)(out + (size_t)eB * E_DIM + e0) = o; }
    if (g0 + 2 < nE) { float4 o; o.x=v2.x*iv2; o.y=v2.y*iv2; o.z=v2.z*iv2; o.w=v2.w*iv2;
        *(float4*)(out + (size_t)eC * E_DIM + e0) = o; }
    if (g0 + 3 < nE) { float4 o; o.x=v3.x*iv3; o.y=v3.y*iv3; o.z=v3.z*iv3; o.w=v3.w*iv3;
        *(float4*)(out + (size_t)eD * E_DIM + e0) = o; }
}

// ---------------------------------------------------------------------------
// Fallback (round-2 kernel, proven 121us) if workspace is unavailable.
// ---------------------------------------------------------------------------
__launch_bounds__(256, 8)
__global__ void gatne_fallback(
    const float* __restrict__ node_embeddings,
    const float* __restrict__ node_type_embeddings,
    const float* __restrict__ trans_weights,
    const float* __restrict__ trans_weights_s1,
    const float* __restrict__ trans_weights_s2,
    const int*   __restrict__ train_inputs,
    const int*   __restrict__ train_types,
    const int*   __restrict__ node_neigh,
    float*       __restrict__ out)
{
    const int b    = blockIdx.x;
    const int tid  = threadIdx.x;
    const int lane = tid & 63;
    const int wv   = tid >> 6;

    __shared__ float s_nte[T_DIM][U_DIM];
    __shared__ float s_att[T_DIM];
    __shared__ float s_agg[U_DIM];
    __shared__ float s_red[4];

    const int* nn = node_neigh + (size_t)b * (T_DIM * NB);
    int my = 0;
    if (lane < 2 * NB) my = nn[wv * NB + (lane < NB ? lane : 30 + lane)];

    const int ni = train_inputs[b];
    const int ty = train_types[b];
    const int e0 = tid * 2;
    const float2 ne = *(const float2*)(node_embeddings + (size_t)ni * E_DIM + e0);

    float a0 = 0.f, a1 = 0.f;
    #pragma unroll
    for (int n = 0; n < NB; ++n) {
        const int i0 = __shfl(my, n, 64);
        const int i1 = __shfl(my, NB + n, 64);
        a0 += node_type_embeddings[(size_t)i0 * (T_DIM * U_DIM) + wv * U_DIM + lane];
        a1 += node_type_embeddings[(size_t)i1 * (T_DIM * U_DIM) + (wv + 4) * U_DIM + lane];
    }
    s_nte[wv][lane]     = a0;
    s_nte[wv + 4][lane] = a1;
    __syncthreads();

    {
        const int t = tid >> 5;
        const int a = tid & 31;
        const float* w1 = trans_weights_s1 + (size_t)ty * (U_DIM * A_DIM) + a;
        float h = 0.f;
        #pragma unroll
        for (int u = 0; u < U_DIM; ++u)
            h = fmaf(s_nte[t][u], w1[u * A_DIM], h);
        float val = tanhf(h) * trans_weights_s2[ty * A_DIM + a];
        #pragma unroll
        for (int off = 16; off > 0; off >>= 1)
            val += __shfl_down(val, off, 32);
        if (a == 0) s_att[t] = val;
    }
    __syncthreads();

    if (tid < U_DIM) {
        const float sc0 = s_att[0], sc1 = s_att[1], sc2 = s_att[2], sc3 = s_att[3];
        const float sc4 = s_att[4], sc5 = s_att[5], sc6 = s_att[6], sc7 = s_att[7];
        const float m = fmaxf(fmaxf(fmaxf(sc0, sc1), fmaxf(sc2, sc3)),
                              fmaxf(fmaxf(sc4, sc5), fmaxf(sc6, sc7)));
        const float x0 = __expf(sc0 - m), x1 = __expf(sc1 - m);
        const float x2 = __expf(sc2 - m), x3 = __expf(sc3 - m);
        const float x4 = __expf(sc4 - m), x5 = __expf(sc5 - m);
        const float x6 = __expf(sc6 - m), x7 = __expf(sc7 - m);
        const float inv_sum = 1.f / (x0 + x1 + x2 + x3 + x4 + x5 + x6 + x7);
        const float acc = x0 * s_nte[0][tid] + x1 * s_nte[1][tid]
                        + x2 * s_nte[2][tid] + x3 * s_nte[3][tid]
                        + x4 * s_nte[4][tid] + x5 * s_nte[5][tid]
                        + x6 * s_nte[6][tid] + x7 * s_nte[7][tid];
        s_agg[tid] = acc * inv_sum;
    }
    __syncthreads();

    const float* wb = trans_weights + (size_t)ty * (U_DIM * E_DIM) + e0;
    float v0 = ne.x, v1 = ne.y;
    #pragma unroll 16
    for (int u = 0; u < U_DIM; ++u) {
        const float av = s_agg[u];
        const float2 w2v = *(const float2*)(wb + (size_t)u * E_DIM);
        v0 = fmaf(av, w2v.x, v0);
        v1 = fmaf(av, w2v.y, v1);
    }

    float ss = v0 * v0 + v1 * v1;
    #pragma unroll
    for (int off = 32; off > 0; off >>= 1)
        ss += __shfl_xor(ss, off, 64);
    if (lane == 0) s_red[wv] = ss;
    __syncthreads();
    const float total = s_red[0] + s_red[1] + s_red[2] + s_red[3];
    const float inv = 1.f / fmaxf(sqrtf(total), 1e-12f);

    float2 o; o.x = v0 * inv; o.y = v1 * inv;
    *(float2*)(out + (size_t)b * E_DIM + e0) = o;
}

extern "C" void kernel_launch(void* const* d_in, const int* in_sizes, int n_in,
                              void* d_out, int out_size, void* d_ws, size_t ws_size,
                              hipStream_t stream) {
    const float* node_embeddings      = (const float*)d_in[0];
    const float* node_type_embeddings = (const float*)d_in[1];
    const float* trans_weights        = (const float*)d_in[2];
    const float* trans_weights_s1     = (const float*)d_in[3];
    const float* trans_weights_s2     = (const float*)d_in[4];
    const int*   train_inputs         = (const int*)d_in[5];
    const int*   train_types          = (const int*)d_in[6];
    const int*   node_neigh           = (const int*)d_in[7];
    float* out = (float*)d_out;

    if (d_ws != nullptr && ws_size >= WS_TOTAL_BYTES) {
        int*   wsi = (int*)d_ws;
        float* agg = (float*)d_ws + WS_IPAD;
        bucket_kernel<<<1, 1024, 0, stream>>>(train_types, wsi);
        gatne_stage1<<<BATCH, 256, 0, stream>>>(
            node_type_embeddings, trans_weights_s1, trans_weights_s2,
            train_types, node_neigh, agg);
        gatne_stage2<<<S2_BLOCKS, 256, 0, stream>>>(
            node_embeddings, trans_weights, train_inputs, wsi, agg, out);
    } else {
        gatne_fallback<<<BATCH, 256, 0, stream>>>(
            node_embeddings, node_type_embeddings, trans_weights,
            trans_weights_s1, trans_weights_s2,
            train_inputs, train_types, node_neigh, out);
    }
}

// Round 8
// 416.092 us; speedup vs baseline: 1.0995x; 1.0995x over previous
//
#include <hip/hip_runtime.h>

#define E_DIM 512
#define U_DIM 64
#define T_DIM 8
#define A_DIM 32
#define NB    10
#define BATCH 8192

// Block per batch element (8192 blocks), 256 threads = 4 waves.
// Best-measured configuration (round 2: 416.7us total, kernel 121us,
// FETCH 95.6MB, WRITE 16.4MB, occupancy 80%, no spill traffic).
// The random 256B-row gather is latency/MSHR-bound at ~1.9TB/s effective;
// float4-widening (r7) and wave-privatization (r0) both regressed it.
__launch_bounds__(256, 8)
__global__ void gatne_kernel(
    const float* __restrict__ node_embeddings,      // [N, 512]
    const float* __restrict__ node_type_embeddings, // [N, 8, 64]
    const float* __restrict__ trans_weights,        // [8, 64, 512]
    const float* __restrict__ trans_weights_s1,     // [8, 64, 32]
    const float* __restrict__ trans_weights_s2,     // [8, 32]
    const int*   __restrict__ train_inputs,         // [B]
    const int*   __restrict__ train_types,          // [B]
    const int*   __restrict__ node_neigh,           // [B, 8, 10]
    float*       __restrict__ out)                  // [B, 512]
{
    const int b    = blockIdx.x;
    const int tid  = threadIdx.x;
    const int lane = tid & 63;
    const int wv   = tid >> 6;     // wave 0..3 handles types wv and wv+4

    __shared__ float s_nte[T_DIM][U_DIM];   // 2 KB
    __shared__ float s_att[T_DIM];
    __shared__ float s_agg[U_DIM];
    __shared__ float s_red[4];

    // ---- per-wave neighbor indices via shfl broadcast (no LDS, no barrier) ----
    // lanes 0..9  -> row t=wv   : nn[wv*10 + lane]
    // lanes 10..19-> row t=wv+4 : nn[(wv+4)*10 + (lane-10)] = nn[wv*10 + 30 + lane]
    const int* nn = node_neigh + (size_t)b * (T_DIM * NB);
    int my = 0;
    if (lane < 2 * NB) my = nn[wv * NB + (lane < NB ? lane : 30 + lane)];

    const int ni = train_inputs[b];   // block-uniform -> scalar loads
    const int ty = train_types[b];

    // ---- prefetch node_embed row early (2 floats per thread, coalesced) ----
    const int e0 = tid * 2;
    const float2 ne = *(const float2*)(node_embeddings + (size_t)ni * E_DIM + e0);

    // ---- gather + neighbor-sum: wave wv does types wv and wv+4 ----
    float a0 = 0.f, a1 = 0.f;
    #pragma unroll
    for (int n = 0; n < NB; ++n) {
        const int i0 = __shfl(my, n, 64);
        const int i1 = __shfl(my, NB + n, 64);
        a0 += node_type_embeddings[(size_t)i0 * (T_DIM * U_DIM) + wv * U_DIM + lane];
        a1 += node_type_embeddings[(size_t)i1 * (T_DIM * U_DIM) + (wv + 4) * U_DIM + lane];
    }
    s_nte[wv][lane]     = a0;
    s_nte[wv + 4][lane] = a1;
    __syncthreads();

    // ---- attention scores: thread (t = tid>>5, a = tid&31) ----
    {
        const int t = tid >> 5;
        const int a = tid & 31;
        const float* w1 = trans_weights_s1 + (size_t)ty * (U_DIM * A_DIM) + a;
        float h = 0.f;
        #pragma unroll
        for (int u = 0; u < U_DIM; ++u)
            h = fmaf(s_nte[t][u], w1[u * A_DIM], h);   // LDS broadcast * L2-hot 128B
        float val = tanhf(h) * trans_weights_s2[ty * A_DIM + a];
        #pragma unroll
        for (int off = 16; off > 0; off >>= 1)
            val += __shfl_down(val, off, 32);
        if (a == 0) s_att[t] = val;                    // raw score
    }
    __syncthreads();

    // ---- softmax (redundant, in-register) fused with agg: threads 0..63 ----
    if (tid < U_DIM) {
        const float sc0 = s_att[0], sc1 = s_att[1], sc2 = s_att[2], sc3 = s_att[3];
        const float sc4 = s_att[4], sc5 = s_att[5], sc6 = s_att[6], sc7 = s_att[7];
        const float m = fmaxf(fmaxf(fmaxf(sc0, sc1), fmaxf(sc2, sc3)),
                              fmaxf(fmaxf(sc4, sc5), fmaxf(sc6, sc7)));
        const float x0 = __expf(sc0 - m), x1 = __expf(sc1 - m);
        const float x2 = __expf(sc2 - m), x3 = __expf(sc3 - m);
        const float x4 = __expf(sc4 - m), x5 = __expf(sc5 - m);
        const float x6 = __expf(sc6 - m), x7 = __expf(sc7 - m);
        const float inv_sum = 1.f / (x0 + x1 + x2 + x3 + x4 + x5 + x6 + x7);
        const float acc = x0 * s_nte[0][tid] + x1 * s_nte[1][tid]
                        + x2 * s_nte[2][tid] + x3 * s_nte[3][tid]
                        + x4 * s_nte[4][tid] + x5 * s_nte[5][tid]
                        + x6 * s_nte[6][tid] + x7 * s_nte[7][tid];
        s_agg[tid] = acc * inv_sum;
    }
    __syncthreads();

    // ---- out[e] = node_embed[e] + sum_u agg[u] * w[ty,u,e] ----
    const float* wb = trans_weights + (size_t)ty * (U_DIM * E_DIM) + e0;
    float v0 = ne.x, v1 = ne.y;
    #pragma unroll 16
    for (int u = 0; u < U_DIM; ++u) {
        const float av = s_agg[u];                     // LDS broadcast
        const float2 w2v = *(const float2*)(wb + (size_t)u * E_DIM);
        v0 = fmaf(av, w2v.x, v0);
        v1 = fmaf(av, w2v.y, v1);
    }

    // ---- block L2-norm: wave butterfly + 4-entry LDS combine ----
    float ss = v0 * v0 + v1 * v1;
    #pragma unroll
    for (int off = 32; off > 0; off >>= 1)
        ss += __shfl_xor(ss, off, 64);
    if (lane == 0) s_red[wv] = ss;
    __syncthreads();
    const float total = s_red[0] + s_red[1] + s_red[2] + s_red[3];
    const float inv = 1.f / fmaxf(sqrtf(total), 1e-12f);

    float2 o; o.x = v0 * inv; o.y = v1 * inv;
    *(float2*)(out + (size_t)b * E_DIM + e0) = o;
}

extern "C" void kernel_launch(void* const* d_in, const int* in_sizes, int n_in,
                              void* d_out, int out_size, void* d_ws, size_t ws_size,
                              hipStream_t stream) {
    const float* node_embeddings      = (const float*)d_in[0];
    const float* node_type_embeddings = (const float*)d_in[1];
    const float* trans_weights        = (const float*)d_in[2];
    const float* trans_weights_s1     = (const float*)d_in[3];
    const float* trans_weights_s2     = (const float*)d_in[4];
    const int*   train_inputs         = (const int*)d_in[5];
    const int*   train_types          = (const int*)d_in[6];
    const int*   node_neigh           = (const int*)d_in[7];
    float* out = (float*)d_out;

    gatne_kernel<<<BATCH, 256, 0, stream>>>(
        node_embeddings, node_type_embeddings, trans_weights,
        trans_weights_s1, trans_weights_s2,
        train_inputs, train_types, node_neigh, out);
}